// Round 1
// baseline (264.603 us; speedup 1.0000x reference)
//
#include <hip/hip_runtime.h>
#include <stdint.h>

// GAT 3-layer + linear head, MI355X (gfx950).
// I/O is FP32 (per reference). Internals: bf16 MFMA for h and att@h
// (softmax-averaging damps bf16 rounding); logits and final linear in fp32.
// R7: k_attn de-VALU-ification.
//   (a) exp factored out of the inner loop: exp2(leaky(es+ed)) ==
//       max(Es*Ed, Fs*Fd) with Es=2^es, Fs=2^(0.2es) etc. precomputed per
//       node in k_h (4 exp2/node vs 33.5M exp2/layer in the j-loop).
//   (b) softmax denominator via an all-ones MFMA B-operand: D = P @ 1 gives
//       each lane its 4 row-sums in the C-layout the epilogue already uses;
//       consistent with rounded bf16 P, removes per-element dacc + shfl.
//   (c) native (__bf16) casts so the compiler emits v_cvt_pk_bf16_f32
//       instead of the 4-op manual RNE sequence.

typedef unsigned short u16;
typedef __bf16 bf16x8 __attribute__((ext_vector_type(8)));
typedef float f32x4 __attribute__((ext_vector_type(4)));
typedef u16 u16x8 __attribute__((ext_vector_type(8)));

#define LOG2E 1.44269504088896340736f

__device__ __forceinline__ float b2f(u16 u) {
    union { unsigned int i; float f; } v; v.i = ((unsigned int)u) << 16; return v.f;
}
__device__ __forceinline__ u16 f2b(float f) {   // RNE round to bf16
    union { float f; unsigned int i; } v; v.f = f;
    unsigned int i = v.i;
    return (u16)((i + 0x7fffu + ((i >> 16) & 1u)) >> 16);
}
__device__ __forceinline__ float fast_exp2(float x) {
#if __has_builtin(__builtin_amdgcn_exp2f)
    return __builtin_amdgcn_exp2f(x);
#else
    return exp2f(x);
#endif
}

union ABfrag { bf16x8 v; u16x8 u; };

__device__ __forceinline__ void gload_lds16(const u16* g, u16* l) {
    // async global->LDS, 16B/lane, LDS dest = wave-uniform base + lane*16
    __builtin_amdgcn_global_load_lds((const __attribute__((address_space(1))) void*)g,
                                     (__attribute__((address_space(3))) void*)l,
                                     16, 0, 0);
}

// ---------------- k_mask: adjacency bitmask, adjm[row][64] uint32 (bit j of row)
__global__ void __launch_bounds__(256) k_mask(const float* __restrict__ adj,
                                              uint32_t* __restrict__ adjm) {
    const int w = threadIdx.x >> 6, lane = threadIdx.x & 63;
    const int row = blockIdx.x * 4 + w;
    const float* ar = adj + (size_t)row * 2048;
    uint32_t* mr = adjm + (size_t)row * 64;
    for (int j0 = 0; j0 < 2048; j0 += 64) {
        unsigned long long m = __ballot(ar[j0 + lane] > 0.f);
        if (lane == 0) {
            mr[(j0 >> 5)] = (uint32_t)m;
            mr[(j0 >> 5) + 1] = (uint32_t)(m >> 32);
        }
    }
}

// ---------------- prep: bf16-transpose W's, u = (W @ a)*log2e (fp32)
__global__ void k_prep(const float* __restrict__ W1, const float* __restrict__ W2,
                       const float* __restrict__ W3,
                       const float* __restrict__ a1s, const float* __restrict__ a1d,
                       const float* __restrict__ a2s, const float* __restrict__ a2d,
                       const float* __restrict__ a3s, const float* __restrict__ a3d,
                       u16* __restrict__ Wt1, u16* __restrict__ Wt2, u16* __restrict__ Wt3,
                       float* __restrict__ u1s, float* __restrict__ u1d,
                       float* __restrict__ u2s, float* __restrict__ u2d,
                       float* __restrict__ u3s, float* __restrict__ u3d) {
    if (blockIdx.x == 160) {                 // u-vectors: fp32 matvecs, trivial size
        int f = threadIdx.x;
        if (f < 128) {
            float s1 = 0.f, d1 = 0.f, s2 = 0.f, d2 = 0.f, s3 = 0.f, d3 = 0.f;
            for (int o = 0; o < 128; ++o) { float w = W1[f * 128 + o]; s1 += w * a1s[o]; d1 += w * a1d[o]; }
            for (int o = 0; o < 128; ++o) { float w = W2[f * 128 + o]; s2 += w * a2s[o]; d2 += w * a2d[o]; }
            for (int o = 0; o <  64; ++o) { float w = W3[f *  64 + o]; s3 += w * a3s[o]; d3 += w * a3d[o]; }
            u1s[f] = s1 * LOG2E; u1d[f] = d1 * LOG2E;
            u2s[f] = s2 * LOG2E; u2d[f] = d2 * LOG2E;
            u3s[f] = s3 * LOG2E; u3d[f] = d3 * LOG2E;
        }
        return;
    }
    int idx = blockIdx.x * 256 + threadIdx.x;
    if (idx < 16384) {                       // W1: [128,128] -> Wt1[o][f] bf16
        int f = idx >> 7, o = idx & 127;
        Wt1[o * 128 + f] = f2b(W1[idx]);
    } else if (idx < 32768) {                // W2
        int j = idx - 16384; int f = j >> 7, o = j & 127;
        Wt2[o * 128 + f] = f2b(W2[j]);
    } else if (idx < 40960) {                // W3: [128,64] -> Wt3[o][f]
        int j = idx - 32768; int f = j >> 6, o = j & 63;
        Wt3[o * 128 + f] = f2b(W3[j]);
    }
}

// ---------------- k_h: h = act @ W (bf16 MFMA) -> h^T bf16;
// logits -> exponentials: esf[i] = (2^es, 2^0.2es), edf[i] = (2^ed, 2^0.2ed)
// grid (8, 32) = (b, nblk), block 256 (4 waves x 16 rows). K = 128 always.
template <int F, bool XF32>
__global__ void __launch_bounds__(256) k_h(const void* __restrict__ xv,
                                           const u16* __restrict__ Wt,
                                           const float* __restrict__ us,
                                           const float* __restrict__ ud,
                                           u16* __restrict__ h_t,
                                           float* __restrict__ esf,
                                           float* __restrict__ edf) {
    constexpr int NT = F / 16;
    constexpr int TNP = 72;                  // padded n-stride (144B = 9x16B)
    __shared__ __align__(16) u16 hl[F * TNP];

    const int b = blockIdx.x;
    const int nblk = blockIdx.y;
    const int tid = threadIdx.x;
    const int w = tid >> 6, lane = tid & 63;
    const int quad = lane >> 4, l15 = lane & 15;
    const int n0w = nblk * 64 + w * 16;
    const int i_a = n0w + l15;               // A-operand row (m = lane&15)

    ABfrag afr[4];
    float ps = 0.f, pd = 0.f;
    if (XF32) {
        const float* xr = (const float*)xv + ((size_t)(b * 2048 + i_a)) * 128;
#pragma unroll
        for (int kk = 0; kk < 4; ++kk) {
            const int o8 = kk * 32 + quad * 8;
            float4 x0 = *reinterpret_cast<const float4*>(xr + o8);
            float4 x1 = *reinterpret_cast<const float4*>(xr + o8 + 4);
            float4 s0 = *reinterpret_cast<const float4*>(us + o8);
            float4 s1 = *reinterpret_cast<const float4*>(us + o8 + 4);
            float4 d0 = *reinterpret_cast<const float4*>(ud + o8);
            float4 d1 = *reinterpret_cast<const float4*>(ud + o8 + 4);
            ps += x0.x * s0.x + x0.y * s0.y + x0.z * s0.z + x0.w * s0.w
                + x1.x * s1.x + x1.y * s1.y + x1.z * s1.z + x1.w * s1.w;
            pd += x0.x * d0.x + x0.y * d0.y + x0.z * d0.z + x0.w * d0.w
                + x1.x * d1.x + x1.y * d1.y + x1.z * d1.z + x1.w * d1.w;
            afr[kk].u[0] = f2b(x0.x); afr[kk].u[1] = f2b(x0.y);
            afr[kk].u[2] = f2b(x0.z); afr[kk].u[3] = f2b(x0.w);
            afr[kk].u[4] = f2b(x1.x); afr[kk].u[5] = f2b(x1.y);
            afr[kk].u[6] = f2b(x1.z); afr[kk].u[7] = f2b(x1.w);
        }
    } else {
        const u16* xr = (const u16*)xv + ((size_t)(b * 2048 + i_a)) * 128;
#pragma unroll
        for (int kk = 0; kk < 4; ++kk) {
            const int o8 = kk * 32 + quad * 8;
            u16x8 xa = *reinterpret_cast<const u16x8*>(xr + o8);
            afr[kk].u = xa;
            float4 s0 = *reinterpret_cast<const float4*>(us + o8);
            float4 s1 = *reinterpret_cast<const float4*>(us + o8 + 4);
            float4 d0 = *reinterpret_cast<const float4*>(ud + o8);
            float4 d1 = *reinterpret_cast<const float4*>(ud + o8 + 4);
            float xf[8];
#pragma unroll
            for (int j = 0; j < 8; ++j) xf[j] = b2f(xa[j]);
            ps += xf[0] * s0.x + xf[1] * s0.y + xf[2] * s0.z + xf[3] * s0.w
                + xf[4] * s1.x + xf[5] * s1.y + xf[6] * s1.z + xf[7] * s1.w;
            pd += xf[0] * d0.x + xf[1] * d0.y + xf[2] * d0.z + xf[3] * d0.w
                + xf[4] * d1.x + xf[5] * d1.y + xf[6] * d1.z + xf[7] * d1.w;
        }
    }
    // reduce logit partials across the 4 quads sharing l15 (full 128-dot)
    ps += __shfl_xor(ps, 16, 64); ps += __shfl_xor(ps, 32, 64);
    pd += __shfl_xor(pd, 16, 64); pd += __shfl_xor(pd, 32, 64);
    if (quad == 0) {
        const size_t idx = (size_t)(b * 2048 + i_a) * 2;
        float2 sv; sv.x = fast_exp2(ps); sv.y = fast_exp2(0.2f * ps);
        float2 dv; dv.x = fast_exp2(pd); dv.y = fast_exp2(0.2f * pd);
        *reinterpret_cast<float2*>(esf + idx) = sv;   // (Es, Fs)
        *reinterpret_cast<float2*>(edf + idx) = dv;   // (Ed, Fd)
    }

    f32x4 acc[NT];
#pragma unroll
    for (int nt = 0; nt < NT; ++nt) acc[nt] = (f32x4){0.f, 0.f, 0.f, 0.f};
#pragma unroll
    for (int kk = 0; kk < 4; ++kk) {
#pragma unroll
        for (int nt = 0; nt < NT; ++nt) {
            bf16x8 bfv = *reinterpret_cast<const bf16x8*>(
                Wt + (nt * 16 + l15) * 128 + kk * 32 + quad * 8);
            acc[nt] = __builtin_amdgcn_mfma_f32_16x16x32_bf16(afr[kk].v, bfv, acc[nt], 0, 0, 0);
        }
    }

    // stage transposed tile to LDS (D: col=l15 -> o, row=quad*4+r -> i), then
    // coalesced global write of h^T[b][o][n]
#pragma unroll
    for (int nt = 0; nt < NT; ++nt)
#pragma unroll
        for (int r = 0; r < 4; ++r)
            hl[(nt * 16 + l15) * TNP + w * 16 + quad * 4 + r] = f2b(acc[nt][r]);
    __syncthreads();
    if (tid < F * 2) {
        int o = tid >> 1, half = tid & 1;
        const u16* src = hl + o * TNP + half * 32;
        u16* dst = h_t + ((size_t)(b * F + o)) * 2048 + nblk * 64 + half * 32;
#pragma unroll
        for (int c = 0; c < 4; ++c)
            *reinterpret_cast<u16x8*>(dst + c * 8) =
                *reinterpret_cast<const u16x8*>(src + c * 8);
    }
}

// ---------------- k_attn: fused masked-softmax(P) @ H, software-pipelined MFMA.
// grid (8, 32) = (b, iblk), block 512 = 2 j-groups x 4 waves x 16 i-rows.
// P built VALU-lean: P_ij = max(Es_i*Ed_j, Fs_i*Fd_j) masked (no exp in loop);
// denominator via P @ ones MFMA (rides the matrix pipe, layout-matched).
template <int F, bool OUT_F32>
__global__ void __launch_bounds__(512) k_attn(const float* __restrict__ esf,
                                              const float* __restrict__ edf,
                                              const uint32_t* __restrict__ adjm,
                                              const u16* __restrict__ h_t,
                                              void* __restrict__ outp) {
    constexpr int NT = F / 16;
    __shared__ __align__(16) u16 Ht[2][2][F * 64];  // [grp][buf], xor-swizzled chunks
    float* accLDS = (float*)&Ht[0][0][0];           // combine area (aliases tiles, used after)

    const int b = blockIdx.x;
    const int iblk = blockIdx.y;
    const int tid = threadIdx.x;
    const int grp = tid >> 8;                 // j-group 0/1
    const int t8 = tid & 255;
    const int w = t8 >> 6;                    // wave-within-group
    const int lane = tid & 63;
    const int quad = lane >> 4, l15 = lane & 15;
    const int i_a = iblk * 64 + w * 16 + l15;

    const float2 esp = *reinterpret_cast<const float2*>(esf + ((size_t)(b * 2048 + i_a)) * 2);
    const float Es = esp.x, Fs = esp.y;
    const float* edb = edf + (size_t)b * 4096;      // (Ed,Fd) float2 per j
    const uint2* mrow = (const uint2*)(adjm + (size_t)i_a * 64);
    const u16* hb = h_t + (size_t)b * F * 2048;

    const int lro = lane >> 3;
    const int lcp = lane & 7;
    const int jt0 = grp * 16;                 // this group's jt range [jt0, jt0+16)

    ABfrag onesf;                              // all-ones B operand (denominator)
#pragma unroll
    for (int j = 0; j < 8; ++j) onesf.u[j] = 0x3F80;   // bf16(1.0)

    f32x4 acc[NT];
#pragma unroll
    for (int nt = 0; nt < NT; ++nt) acc[nt] = (f32x4){0.f, 0.f, 0.f, 0.f};
    f32x4 dccc = (f32x4){0.f, 0.f, 0.f, 0.f};

    // ---- prologue: stage this group's tile 0 + prefetch regs
    {
        const int j0 = jt0 * 64;
#pragma unroll
        for (int it = 0; it < F / 32; ++it) {
            int ro = (it * 4 + w) * 8 + lro;
            int c = lcp ^ (ro & 7);
            gload_lds16(hb + (size_t)ro * 2048 + j0 + c * 8, &Ht[grp][0][(it * 4 + w) * 512]);
        }
    }
    f32x4 ec[8];
    {
        const float* eb = edb + (size_t)(jt0 * 64 + quad * 8) * 2;
#pragma unroll
        for (int q = 0; q < 4; ++q) ec[q] = *reinterpret_cast<const f32x4*>(eb + q * 4);
#pragma unroll
        for (int q = 0; q < 4; ++q) ec[4 + q] = *reinterpret_cast<const f32x4*>(eb + 64 + q * 4);
    }
    uint2 mc = mrow[jt0];
    __syncthreads();                          // both groups' tile 0 staged

#pragma unroll 2
    for (int jj = 0; jj < 16; ++jj) {
        const int cur = jj & 1, nxt = cur ^ 1;
        f32x4 en[8]; uint2 mn;
        if (jj < 15) {
            const int j1 = (jt0 + jj + 1) * 64;
#pragma unroll
            for (int it = 0; it < F / 32; ++it) {
                int ro = (it * 4 + w) * 8 + lro;
                int c = lcp ^ (ro & 7);
                gload_lds16(hb + (size_t)ro * 2048 + j1 + c * 8, &Ht[grp][nxt][(it * 4 + w) * 512]);
            }
            const float* eb = edb + (size_t)(j1 + quad * 8) * 2;
#pragma unroll
            for (int q = 0; q < 4; ++q) en[q] = *reinterpret_cast<const f32x4*>(eb + q * 4);
#pragma unroll
            for (int q = 0; q < 4; ++q) en[4 + q] = *reinterpret_cast<const f32x4*>(eb + 64 + q * 4);
            mn = mrow[jt0 + jj + 1];
        }

        // P fragments in A-operand layout: max(Es*Ed, Fs*Fd), bit-masked.
        ABfrag af[2];
#pragma unroll
        for (int kk = 0; kk < 2; ++kk) {
            const uint32_t word = kk ? mc.y : mc.x;
#pragma unroll
            for (int px = 0; px < 4; ++px) {
                const f32x4 q = ec[kk * 4 + px];          // (Ed0,Fd0,Ed1,Fd1)
                float w0 = fmaxf(Es * q.x, Fs * q.y);
                float w1 = fmaxf(Es * q.z, Fs * q.w);
                const uint32_t s0 = 0u - ((word >> (quad * 8 + px * 2)) & 1u);
                const uint32_t s1 = 0u - ((word >> (quad * 8 + px * 2 + 1)) & 1u);
                w0 = __uint_as_float(__float_as_uint(w0) & s0);
                w1 = __uint_as_float(__float_as_uint(w1) & s1);
                af[kk].v[px * 2]     = (__bf16)w0;        // hw v_cvt_pk_bf16_f32
                af[kk].v[px * 2 + 1] = (__bf16)w1;
            }
        }

        // MFMA over current LDS tile (+ ones-column denominator MFMA)
#pragma unroll
        for (int kk = 0; kk < 2; ++kk) {
#pragma unroll
            for (int nt = 0; nt < NT; ++nt) {
                int ob = nt * 16 + l15;
                int c = kk * 4 + quad;
                bf16x8 bfv = *reinterpret_cast<const bf16x8*>(
                    &Ht[grp][cur][ob * 64 + ((c ^ (ob & 7)) * 8)]);
                acc[nt] = __builtin_amdgcn_mfma_f32_16x16x32_bf16(af[kk].v, bfv, acc[nt], 0, 0, 0);
            }
            dccc = __builtin_amdgcn_mfma_f32_16x16x32_bf16(af[kk].v, onesf.v, dccc, 0, 0, 0);
        }

        if (jj < 15) {
#pragma unroll
            for (int q = 0; q < 8; ++q) ec[q] = en[q];
            mc = mn;
        }
        __syncthreads();   // drains next-tile staging; cur consumed before overwrite
    }

    // cross-group combine: grp1 exports acc + denom partials through dead tile LDS
    if (grp == 1) {
#pragma unroll
        for (int nt = 0; nt < NT; ++nt)
            *reinterpret_cast<f32x4*>(&accLDS[(t8 * (NT + 1) + nt) * 4]) = acc[nt];
        *reinterpret_cast<f32x4*>(&accLDS[(t8 * (NT + 1) + NT) * 4]) = dccc;
    }
    __syncthreads();
    if (grp == 0) {
#pragma unroll
        for (int nt = 0; nt < NT; ++nt)
            acc[nt] += *reinterpret_cast<const f32x4*>(&accLDS[(t8 * (NT + 1) + nt) * 4]);
        dccc += *reinterpret_cast<const f32x4*>(&accLDS[(t8 * (NT + 1) + NT) * 4]);
        float dinv[4];
#pragma unroll
        for (int r = 0; r < 4; ++r)
            dinv[r] = 1.0f / fmaxf(dccc[r], 1e-30f);   // dccc[r] = rowsum(P) for row quad*4+r
        const int ib = iblk * 64 + w * 16 + quad * 4;
        if (OUT_F32) {
            float* o3 = (float*)outp;
#pragma unroll
            for (int nt = 0; nt < NT; ++nt)
#pragma unroll
                for (int r = 0; r < 4; ++r) {
                    float vv = fmaxf(acc[nt][r] * dinv[r], 0.f);   // relu
                    o3[((size_t)(b * 2048 + ib + r)) * F + nt * 16 + l15] = vv;
                }
        } else {
            u16* xo = (u16*)outp;
#pragma unroll
            for (int nt = 0; nt < NT; ++nt)
#pragma unroll
                for (int r = 0; r < 4; ++r) {
                    float vv = fmaxf(acc[nt][r] * dinv[r], 0.f);
                    xo[((size_t)(b * 2048 + ib + r)) * F + nt * 16 + l15] = f2b(vv);
                }
        }
    }
}

// ---------------- final linear stage 1: [8,131072] fp32 @ [131072,128] fp32
// grid 512, block 256; block p owns k in [p*256,(p+1)*256); writes pbuf[p][b][o].
__global__ void __launch_bounds__(256) k_lin(const float* __restrict__ o3,
                                             const float* __restrict__ Wlin,
                                             float* __restrict__ pbuf) {
    __shared__ float xc[8][256];
    __shared__ float red[8][8][128];          // [kb][b][o] = 32 KB
    const int tid = threadIdx.x;
    const int k0 = blockIdx.x * 256;
    for (int idx = tid; idx < 2048; idx += 256) {
        int bb = idx >> 8, kk = idx & 255;
        xc[bb][kk] = o3[(size_t)bb * 131072 + k0 + kk];
    }
    __syncthreads();
    const int o4 = tid & 31;                  // float4 output group: o = 4*o4..4*o4+3
    const int kb = tid >> 5;                  // k band: 32 k each
    f32x4 acc[8];
#pragma unroll
    for (int bb = 0; bb < 8; ++bb) acc[bb] = (f32x4){0.f, 0.f, 0.f, 0.f};
    const float* wp = Wlin + (size_t)(k0 + kb * 32) * 128 + o4 * 4;
#pragma unroll 4
    for (int k = 0; k < 32; ++k) {
        f32x4 wv = *reinterpret_cast<const f32x4*>(wp + (size_t)k * 128);
#pragma unroll
        for (int bb = 0; bb < 8; ++bb) acc[bb] += wv * xc[bb][kb * 32 + k];
    }
#pragma unroll
    for (int bb = 0; bb < 8; ++bb)
        *reinterpret_cast<f32x4*>(&red[kb][bb][o4 * 4]) = acc[bb];
    __syncthreads();
    // fold 8 k-bands: thread handles 4 flat outputs
    const int f = tid * 4;
    const int bb = f >> 7, o = f & 127;
    f32x4 s = (f32x4){0.f, 0.f, 0.f, 0.f};
#pragma unroll
    for (int k2 = 0; k2 < 8; ++k2) s += *reinterpret_cast<const f32x4*>(&red[k2][bb][o]);
    *reinterpret_cast<f32x4*>(&pbuf[(size_t)blockIdx.x * 1024 + f]) = s;
}

// ---------------- stage 2: fold 512 partials + bias -> out
// grid 64 x 256: block owns 16 outputs; 16 threads/output sum strided partials.
__global__ void __launch_bounds__(256) k_bias(const float* __restrict__ pbuf,
                                              const float* __restrict__ blin,
                                              float* __restrict__ out) {
    __shared__ float red[256];
    const int tid = threadIdx.x;
    const int p16 = tid >> 4;                 // 16 p-groups
    const int fo = tid & 15;
    const int f0 = blockIdx.x * 16;
    float s = 0.f;
#pragma unroll 4
    for (int p = p16; p < 512; p += 16)
        s += pbuf[(size_t)p * 1024 + f0 + fo];
    red[tid] = s;
    __syncthreads();
    if (tid < 16) {
        float t = 0.f;
#pragma unroll
        for (int k = 0; k < 16; ++k) t += red[k * 16 + tid];
        out[f0 + tid] = t + blin[(f0 + tid) & 127];
    }
}

extern "C" void kernel_launch(void* const* d_in, const int* in_sizes, int n_in,
                              void* d_out, int out_size, void* d_ws, size_t ws_size,
                              hipStream_t stream) {
    (void)in_sizes; (void)n_in; (void)out_size;
    const float* x    = (const float*)d_in[0];
    const float* adj  = (const float*)d_in[1];
    const float* W1   = (const float*)d_in[2];
    const float* a1s  = (const float*)d_in[3];
    const float* a1d  = (const float*)d_in[4];
    const float* W2   = (const float*)d_in[5];
    const float* a2s  = (const float*)d_in[6];
    const float* a2d  = (const float*)d_in[7];
    const float* W3   = (const float*)d_in[8];
    const float* a3s  = (const float*)d_in[9];
    const float* a3d  = (const float*)d_in[10];
    const float* Wlin = (const float*)d_in[11];
    const float* blin = (const float*)d_in[12];

    // ---- workspace layout (adaptive; never early-return) ----
    char* ws = (char*)d_ws;
    u16*   h_t = (u16*)ws;                          // 4 MB  [8][F][2048] bf16
    size_t off = (size_t)4 << 20;
    float* esf = (float*)(ws + off); off += 131072; // [8][2048] x (Es,Fs)
    float* edf = (float*)(ws + off); off += 131072; // [8][2048] x (Ed,Fd)
    u16*   Wt1 = (u16*)(ws + off);   off += 32768;
    u16*   Wt2 = (u16*)(ws + off);   off += 32768;
    u16*   Wt3 = (u16*)(ws + off);   off += 16384;
    float* u1s = (float*)(ws + off); off += 512;
    float* u1d = (float*)(ws + off); off += 512;
    float* u2s = (float*)(ws + off); off += 512;
    float* u2d = (float*)(ws + off); off += 512;
    float* u3s = (float*)(ws + off); off += 512;
    float* u3d = (float*)(ws + off); off += 512;
    uint32_t* adjm = (uint32_t*)(ws + off); off += 524288;    // [2048][64] bitmask
    float* pbuf = (float*)(ws + off); off += (size_t)512 * 1024 * 4;  // 2 MB partials
    // activation ping (bf16 [8][2048][128] = 4MB) aliases layer-3 fp32 out
    // ([8][2048][64] fp32 = 4MB): disjoint live ranges. Fallback: alias the x
    // input (16MB fp32; dead after layer-1 k_h; restored by harness pre-launch).
    u16* actA;
    if (ws_size >= off + ((size_t)4 << 20)) {
        actA = (u16*)(ws + off);
    } else {
        actA = (u16*)d_in[0];
    }
    float* o3 = (float*)actA;

    dim3 g(8, 32);
    k_mask<<<512, 256, 0, stream>>>(adj, adjm);
    k_prep<<<161, 256, 0, stream>>>(W1, W2, W3, a1s, a1d, a2s, a2d, a3s, a3d,
                                    Wt1, Wt2, Wt3, u1s, u1d, u2s, u2d, u3s, u3d);

    k_h<128, true ><<<g, 256, 0, stream>>>((const void*)x, Wt1, u1s, u1d, h_t, esf, edf);
    k_attn<128, false><<<g, 512, 0, stream>>>(esf, edf, adjm, h_t, (void*)actA);

    k_h<128, false><<<g, 256, 0, stream>>>((const void*)actA, Wt2, u2s, u2d, h_t, esf, edf);
    k_attn<128, false><<<g, 512, 0, stream>>>(esf, edf, adjm, h_t, (void*)actA);

    k_h<64, false><<<g, 256, 0, stream>>>((const void*)actA, Wt3, u3s, u3d, h_t, esf, edf);
    k_attn<64, true ><<<g, 512, 0, stream>>>(esf, edf, adjm, h_t, (void*)o3);

    k_lin<<<512, 256, 0, stream>>>(o3, Wlin, pbuf);
    k_bias<<<64, 256, 0, stream>>>(pbuf, blin, (float*)d_out);
}

// Round 2
// 240.423 us; speedup vs baseline: 1.1006x; 1.1006x over previous
//
#include <hip/hip_runtime.h>
#include <stdint.h>

// GAT 3-layer + linear head, MI355X (gfx950).
// I/O is FP32 (per reference). Internals: bf16 MFMA for h and att@h
// (softmax-averaging damps bf16 rounding); logits and final linear in fp32.
// R8: k_attn pipeline de-serialization (T3+T4+T5).
//   - 3-slot LDS tile ring, raw s_barrier + counted s_waitcnt vmcnt(G):
//     tile j+2 issued at iter j, waited at iter j+2 (2 iters of flight);
//     vmcnt never drains to 0 inside the loop (R7 drained every iter via
//     __syncthreads -> full lockstep stall of all 8 waves x 16 iters).
//   - e-vectors (Ed,Fd) and adjacency-mask pairs staged to LDS once in the
//     prologue; loop-body vmem = staging loads ONLY, so the vmcnt counting
//     is exact (FIFO) and compiler e-waits (lgkm) can't drain the queue.
//   - masks XOR-swizzled in LDS (16 rows same-bank otherwise).
//   - s_setprio(1) around the MFMA cluster.

typedef unsigned short u16;
typedef __bf16 bf16x8 __attribute__((ext_vector_type(8)));
typedef float f32x4 __attribute__((ext_vector_type(4)));
typedef u16 u16x8 __attribute__((ext_vector_type(8)));

#define LOG2E 1.44269504088896340736f

__device__ __forceinline__ float b2f(u16 u) {
    union { unsigned int i; float f; } v; v.i = ((unsigned int)u) << 16; return v.f;
}
__device__ __forceinline__ u16 f2b(float f) {   // RNE round to bf16
    union { float f; unsigned int i; } v; v.f = f;
    unsigned int i = v.i;
    return (u16)((i + 0x7fffu + ((i >> 16) & 1u)) >> 16);
}
__device__ __forceinline__ float fast_exp2(float x) {
#if __has_builtin(__builtin_amdgcn_exp2f)
    return __builtin_amdgcn_exp2f(x);
#else
    return exp2f(x);
#endif
}

union ABfrag { bf16x8 v; u16x8 u; };

__device__ __forceinline__ void gload_lds16(const u16* g, u16* l) {
    // async global->LDS, 16B/lane, LDS dest = wave-uniform base + lane*16
    __builtin_amdgcn_global_load_lds((const __attribute__((address_space(1))) void*)g,
                                     (__attribute__((address_space(3))) void*)l,
                                     16, 0, 0);
}

template <int N>
__device__ __forceinline__ void wait_vmcnt() {
    asm volatile("s_waitcnt vmcnt(%0)" :: "i"(N) : "memory");
}
__device__ __forceinline__ void pipe_barrier() {
    __builtin_amdgcn_s_barrier();
    asm volatile("" ::: "memory");   // pin loads below the barrier
}

// ---------------- k_mask: adjacency bitmask, adjm[row][64] uint32 (bit j of row)
__global__ void __launch_bounds__(256) k_mask(const float* __restrict__ adj,
                                              uint32_t* __restrict__ adjm) {
    const int w = threadIdx.x >> 6, lane = threadIdx.x & 63;
    const int row = blockIdx.x * 4 + w;
    const float* ar = adj + (size_t)row * 2048;
    uint32_t* mr = adjm + (size_t)row * 64;
    for (int j0 = 0; j0 < 2048; j0 += 64) {
        unsigned long long m = __ballot(ar[j0 + lane] > 0.f);
        if (lane == 0) {
            mr[(j0 >> 5)] = (uint32_t)m;
            mr[(j0 >> 5) + 1] = (uint32_t)(m >> 32);
        }
    }
}

// ---------------- prep: bf16-transpose W's, u = (W @ a)*log2e (fp32)
__global__ void k_prep(const float* __restrict__ W1, const float* __restrict__ W2,
                       const float* __restrict__ W3,
                       const float* __restrict__ a1s, const float* __restrict__ a1d,
                       const float* __restrict__ a2s, const float* __restrict__ a2d,
                       const float* __restrict__ a3s, const float* __restrict__ a3d,
                       u16* __restrict__ Wt1, u16* __restrict__ Wt2, u16* __restrict__ Wt3,
                       float* __restrict__ u1s, float* __restrict__ u1d,
                       float* __restrict__ u2s, float* __restrict__ u2d,
                       float* __restrict__ u3s, float* __restrict__ u3d) {
    if (blockIdx.x == 160) {                 // u-vectors: fp32 matvecs, trivial size
        int f = threadIdx.x;
        if (f < 128) {
            float s1 = 0.f, d1 = 0.f, s2 = 0.f, d2 = 0.f, s3 = 0.f, d3 = 0.f;
            for (int o = 0; o < 128; ++o) { float w = W1[f * 128 + o]; s1 += w * a1s[o]; d1 += w * a1d[o]; }
            for (int o = 0; o < 128; ++o) { float w = W2[f * 128 + o]; s2 += w * a2s[o]; d2 += w * a2d[o]; }
            for (int o = 0; o <  64; ++o) { float w = W3[f *  64 + o]; s3 += w * a3s[o]; d3 += w * a3d[o]; }
            u1s[f] = s1 * LOG2E; u1d[f] = d1 * LOG2E;
            u2s[f] = s2 * LOG2E; u2d[f] = d2 * LOG2E;
            u3s[f] = s3 * LOG2E; u3d[f] = d3 * LOG2E;
        }
        return;
    }
    int idx = blockIdx.x * 256 + threadIdx.x;
    if (idx < 16384) {                       // W1: [128,128] -> Wt1[o][f] bf16
        int f = idx >> 7, o = idx & 127;
        Wt1[o * 128 + f] = f2b(W1[idx]);
    } else if (idx < 32768) {                // W2
        int j = idx - 16384; int f = j >> 7, o = j & 127;
        Wt2[o * 128 + f] = f2b(W2[j]);
    } else if (idx < 40960) {                // W3: [128,64] -> Wt3[o][f]
        int j = idx - 32768; int f = j >> 6, o = j & 63;
        Wt3[o * 128 + f] = f2b(W3[j]);
    }
}

// ---------------- k_h: h = act @ W (bf16 MFMA) -> h^T bf16;
// logits -> exponentials: esf[i] = (2^es, 2^0.2es), edf[i] = (2^ed, 2^0.2ed)
// grid (8, 32) = (b, nblk), block 256 (4 waves x 16 rows). K = 128 always.
template <int F, bool XF32>
__global__ void __launch_bounds__(256) k_h(const void* __restrict__ xv,
                                           const u16* __restrict__ Wt,
                                           const float* __restrict__ us,
                                           const float* __restrict__ ud,
                                           u16* __restrict__ h_t,
                                           float* __restrict__ esf,
                                           float* __restrict__ edf) {
    constexpr int NT = F / 16;
    constexpr int TNP = 72;                  // padded n-stride (144B = 9x16B)
    __shared__ __align__(16) u16 hl[F * TNP];

    const int b = blockIdx.x;
    const int nblk = blockIdx.y;
    const int tid = threadIdx.x;
    const int w = tid >> 6, lane = tid & 63;
    const int quad = lane >> 4, l15 = lane & 15;
    const int n0w = nblk * 64 + w * 16;
    const int i_a = n0w + l15;               // A-operand row (m = lane&15)

    ABfrag afr[4];
    float ps = 0.f, pd = 0.f;
    if (XF32) {
        const float* xr = (const float*)xv + ((size_t)(b * 2048 + i_a)) * 128;
#pragma unroll
        for (int kk = 0; kk < 4; ++kk) {
            const int o8 = kk * 32 + quad * 8;
            float4 x0 = *reinterpret_cast<const float4*>(xr + o8);
            float4 x1 = *reinterpret_cast<const float4*>(xr + o8 + 4);
            float4 s0 = *reinterpret_cast<const float4*>(us + o8);
            float4 s1 = *reinterpret_cast<const float4*>(us + o8 + 4);
            float4 d0 = *reinterpret_cast<const float4*>(ud + o8);
            float4 d1 = *reinterpret_cast<const float4*>(ud + o8 + 4);
            ps += x0.x * s0.x + x0.y * s0.y + x0.z * s0.z + x0.w * s0.w
                + x1.x * s1.x + x1.y * s1.y + x1.z * s1.z + x1.w * s1.w;
            pd += x0.x * d0.x + x0.y * d0.y + x0.z * d0.z + x0.w * d0.w
                + x1.x * d1.x + x1.y * d1.y + x1.z * d1.z + x1.w * d1.w;
            afr[kk].u[0] = f2b(x0.x); afr[kk].u[1] = f2b(x0.y);
            afr[kk].u[2] = f2b(x0.z); afr[kk].u[3] = f2b(x0.w);
            afr[kk].u[4] = f2b(x1.x); afr[kk].u[5] = f2b(x1.y);
            afr[kk].u[6] = f2b(x1.z); afr[kk].u[7] = f2b(x1.w);
        }
    } else {
        const u16* xr = (const u16*)xv + ((size_t)(b * 2048 + i_a)) * 128;
#pragma unroll
        for (int kk = 0; kk < 4; ++kk) {
            const int o8 = kk * 32 + quad * 8;
            u16x8 xa = *reinterpret_cast<const u16x8*>(xr + o8);
            afr[kk].u = xa;
            float4 s0 = *reinterpret_cast<const float4*>(us + o8);
            float4 s1 = *reinterpret_cast<const float4*>(us + o8 + 4);
            float4 d0 = *reinterpret_cast<const float4*>(ud + o8);
            float4 d1 = *reinterpret_cast<const float4*>(ud + o8 + 4);
            float xf[8];
#pragma unroll
            for (int j = 0; j < 8; ++j) xf[j] = b2f(xa[j]);
            ps += xf[0] * s0.x + xf[1] * s0.y + xf[2] * s0.z + xf[3] * s0.w
                + xf[4] * s1.x + xf[5] * s1.y + xf[6] * s1.z + xf[7] * s1.w;
            pd += xf[0] * d0.x + xf[1] * d0.y + xf[2] * d0.z + xf[3] * d0.w
                + xf[4] * d1.x + xf[5] * d1.y + xf[6] * d1.z + xf[7] * d1.w;
        }
    }
    // reduce logit partials across the 4 quads sharing l15 (full 128-dot)
    ps += __shfl_xor(ps, 16, 64); ps += __shfl_xor(ps, 32, 64);
    pd += __shfl_xor(pd, 16, 64); pd += __shfl_xor(pd, 32, 64);
    if (quad == 0) {
        const size_t idx = (size_t)(b * 2048 + i_a) * 2;
        float2 sv; sv.x = fast_exp2(ps); sv.y = fast_exp2(0.2f * ps);
        float2 dv; dv.x = fast_exp2(pd); dv.y = fast_exp2(0.2f * pd);
        *reinterpret_cast<float2*>(esf + idx) = sv;   // (Es, Fs)
        *reinterpret_cast<float2*>(edf + idx) = dv;   // (Ed, Fd)
    }

    f32x4 acc[NT];
#pragma unroll
    for (int nt = 0; nt < NT; ++nt) acc[nt] = (f32x4){0.f, 0.f, 0.f, 0.f};
#pragma unroll
    for (int kk = 0; kk < 4; ++kk) {
#pragma unroll
        for (int nt = 0; nt < NT; ++nt) {
            bf16x8 bfv = *reinterpret_cast<const bf16x8*>(
                Wt + (nt * 16 + l15) * 128 + kk * 32 + quad * 8);
            acc[nt] = __builtin_amdgcn_mfma_f32_16x16x32_bf16(afr[kk].v, bfv, acc[nt], 0, 0, 0);
        }
    }

    // stage transposed tile to LDS (D: col=l15 -> o, row=quad*4+r -> i), then
    // coalesced global write of h^T[b][o][n]
#pragma unroll
    for (int nt = 0; nt < NT; ++nt)
#pragma unroll
        for (int r = 0; r < 4; ++r)
            hl[(nt * 16 + l15) * TNP + w * 16 + quad * 4 + r] = f2b(acc[nt][r]);
    __syncthreads();
    if (tid < F * 2) {
        int o = tid >> 1, half = tid & 1;
        const u16* src = hl + o * TNP + half * 32;
        u16* dst = h_t + ((size_t)(b * F + o)) * 2048 + nblk * 64 + half * 32;
#pragma unroll
        for (int c = 0; c < 4; ++c)
            *reinterpret_cast<u16x8*>(dst + c * 8) =
                *reinterpret_cast<const u16x8*>(src + c * 8);
    }
}

// ---------------- k_attn: fused masked-softmax(P) @ H, counted-vmcnt pipeline.
// grid (8, 32) = (b, iblk), block 512 = 2 j-groups x 4 waves x 16 i-rows.
// 3-slot LDS ring per group; tile j+2 issued at iter j, waited (vmcnt(G)) at
// iter j+2; raw s_barrier (no vmcnt(0) drain in the loop). e-vectors + masks
// LDS-resident so staging loads are the only vmem ops in the loop.
template <int F, bool OUT_F32>
__global__ void __launch_bounds__(512) k_attn(const float* __restrict__ esf,
                                              const float* __restrict__ edf,
                                              const uint32_t* __restrict__ adjm,
                                              const u16* __restrict__ h_t,
                                              void* __restrict__ outp) {
    constexpr int NT = F / 16;
    constexpr int G  = F / 32;                       // gload_lds ops per wave per tile
    __shared__ __align__(16) u16 Ht[2][3][F * 64];   // [grp][slot], xor-swizzled tiles
    __shared__ __align__(16) float eL[4096];         // (Ed,Fd) all 2048 j (16 KB)
    __shared__ __align__(16) uint32_t mL[64 * 64];   // mask pairs, xor-swizzled (16 KB)
    float* accLDS = (float*)&Ht[0][0][0];            // combine area (aliases tiles)

    const int b = blockIdx.x;
    const int iblk = blockIdx.y;
    const int tid = threadIdx.x;
    const int grp = tid >> 8;                 // j-group 0/1
    const int t8 = tid & 255;
    const int w = t8 >> 6;                    // wave-within-group
    const int lane = tid & 63;
    const int quad = lane >> 4, l15 = lane & 15;
    const int i_a = iblk * 64 + w * 16 + l15;
    const int r_loc = w * 16 + l15;           // block-local mask row

    const float2 esp = *reinterpret_cast<const float2*>(esf + ((size_t)(b * 2048 + i_a)) * 2);
    const float Es = esp.x, Fs = esp.y;
    const u16* hb = h_t + (size_t)b * F * 2048;

    const int lro = lane >> 3;
    const int lcp = lane & 7;
    const int jt0 = grp * 16;                 // this group's jt range [jt0, jt0+16)

    ABfrag onesf;                             // all-ones B operand (denominator)
#pragma unroll
    for (int j = 0; j < 8; ++j) onesf.u[j] = 0x3F80;   // bf16(1.0)

    f32x4 acc[NT];
#pragma unroll
    for (int nt = 0; nt < NT; ++nt) acc[nt] = (f32x4){0.f, 0.f, 0.f, 0.f};
    f32x4 dccc = (f32x4){0.f, 0.f, 0.f, 0.f};

    // ---- prologue: e-vectors + masks -> LDS (once)
    {
        const float4* esrc = (const float4*)(edf + (size_t)b * 4096);
        float4* edst = (float4*)eL;
#pragma unroll
        for (int t = 0; t < 2; ++t) edst[tid + t * 512] = esrc[tid + t * 512];
        const uint2* msrc = (const uint2*)(adjm + (size_t)(iblk * 64) * 64);
#pragma unroll
        for (int t = 0; t < 4; ++t) {
            int idx = tid + t * 512;
            int r = idx >> 5, k = idx & 31;   // row r (0..63), pair k (0..31)
            uint2 v = msrc[idx];
            *reinterpret_cast<uint2*>((char*)mL + r * 256 + ((k ^ (r & 31)) * 8)) = v;
        }
    }

    auto STAGE = [&](int jt, int slot) {
        const int j0 = jt * 64;
        u16* lbase = &Ht[grp][slot][0];
#pragma unroll
        for (int it = 0; it < G; ++it) {
            int ro = (it * 4 + w) * 8 + lro;
            int c = lcp ^ (ro & 7);
            gload_lds16(hb + (size_t)ro * 2048 + j0 + c * 8, lbase + (it * 4 + w) * 512);
        }
    };

    f32x4 ec[8]; uint2 mc;
    auto loadE = [&](int jt, f32x4* e, uint2& m) {
        const float* eb = eL + (size_t)(jt * 64 + quad * 8) * 2;
#pragma unroll
        for (int q = 0; q < 4; ++q) e[q] = *reinterpret_cast<const f32x4*>(eb + q * 4);
#pragma unroll
        for (int q = 0; q < 4; ++q) e[4 + q] = *reinterpret_cast<const f32x4*>(eb + 64 + q * 4);
        m = *reinterpret_cast<const uint2*>((const char*)mL + r_loc * 256 + ((jt ^ (r_loc & 31)) * 8));
    };

    auto compute = [&](int slot) {
        // P fragments in A-operand layout: max(Es*Ed, Fs*Fd), bit-masked.
        ABfrag af[2];
#pragma unroll
        for (int kk = 0; kk < 2; ++kk) {
            const uint32_t word = kk ? mc.y : mc.x;
#pragma unroll
            for (int px = 0; px < 4; ++px) {
                const f32x4 q = ec[kk * 4 + px];          // (Ed0,Fd0,Ed1,Fd1)
                float w0 = fmaxf(Es * q.x, Fs * q.y);
                float w1 = fmaxf(Es * q.z, Fs * q.w);
                const uint32_t s0 = 0u - ((word >> (quad * 8 + px * 2)) & 1u);
                const uint32_t s1 = 0u - ((word >> (quad * 8 + px * 2 + 1)) & 1u);
                w0 = __uint_as_float(__float_as_uint(w0) & s0);
                w1 = __uint_as_float(__float_as_uint(w1) & s1);
                af[kk].v[px * 2]     = (__bf16)w0;        // hw v_cvt_pk_bf16_f32
                af[kk].v[px * 2 + 1] = (__bf16)w1;
            }
        }
        const u16* tb = &Ht[grp][slot][0];
        __builtin_amdgcn_s_setprio(1);
#pragma unroll
        for (int kk = 0; kk < 2; ++kk) {
#pragma unroll
            for (int nt = 0; nt < NT; ++nt) {
                int ob = nt * 16 + l15;
                int c = kk * 4 + quad;
                bf16x8 bfv = *reinterpret_cast<const bf16x8*>(
                    tb + ob * 64 + ((c ^ (ob & 7)) * 8));
                acc[nt] = __builtin_amdgcn_mfma_f32_16x16x32_bf16(af[kk].v, bfv, acc[nt], 0, 0, 0);
            }
            dccc = __builtin_amdgcn_mfma_f32_16x16x32_bf16(af[kk].v, onesf.v, dccc, 0, 0, 0);
        }
        __builtin_amdgcn_s_setprio(0);
    };

    __syncthreads();                          // eL/mL visible (one-time full drain)
    loadE(jt0, ec, mc);                       // regs for tile 0
    STAGE(jt0, 0);                            // tiles 0,1 in flight
    STAGE(jt0 + 1, 1);

    int sc = 0, sp = 2;
    for (int jj = 0; jj < 15; ++jj) {
        wait_vmcnt<G>();                      // tile jj landed; tile jj+1 stays in flight
        pipe_barrier();                       // all waves' tile-jj DMA visible
        if (jj < 14) STAGE(jt0 + jj + 2, sp); // 2-iter-deep prefetch
        f32x4 en[8]; uint2 mn;
        loadE(jt0 + jj + 1, en, mn);          // LDS reads (lgkm domain)
        compute(sc);
#pragma unroll
        for (int q = 0; q < 8; ++q) ec[q] = en[q];
        mc = mn;
        sc = (sc == 2) ? 0 : sc + 1;
        sp = (sp == 2) ? 0 : sp + 1;
    }
    wait_vmcnt<0>();                          // last tile
    pipe_barrier();
    compute(sc);

    __syncthreads();                          // tile reads done; accLDS alias safe
    // cross-group combine: grp1 exports acc + denom partials through dead tile LDS
    if (grp == 1) {
#pragma unroll
        for (int nt = 0; nt < NT; ++nt)
            *reinterpret_cast<f32x4*>(&accLDS[(t8 * (NT + 1) + nt) * 4]) = acc[nt];
        *reinterpret_cast<f32x4*>(&accLDS[(t8 * (NT + 1) + NT) * 4]) = dccc;
    }
    __syncthreads();
    if (grp == 0) {
#pragma unroll
        for (int nt = 0; nt < NT; ++nt)
            acc[nt] += *reinterpret_cast<const f32x4*>(&accLDS[(t8 * (NT + 1) + nt) * 4]);
        dccc += *reinterpret_cast<const f32x4*>(&accLDS[(t8 * (NT + 1) + NT) * 4]);
        float dinv[4];
#pragma unroll
        for (int r = 0; r < 4; ++r)
            dinv[r] = 1.0f / fmaxf(dccc[r], 1e-30f);   // dccc[r] = rowsum(P) for row quad*4+r
        const int ib = iblk * 64 + w * 16 + quad * 4;
        if (OUT_F32) {
            float* o3 = (float*)outp;
#pragma unroll
            for (int nt = 0; nt < NT; ++nt)
#pragma unroll
                for (int r = 0; r < 4; ++r) {
                    float vv = fmaxf(acc[nt][r] * dinv[r], 0.f);   // relu
                    o3[((size_t)(b * 2048 + ib + r)) * F + nt * 16 + l15] = vv;
                }
        } else {
            u16* xo = (u16*)outp;
#pragma unroll
            for (int nt = 0; nt < NT; ++nt)
#pragma unroll
                for (int r = 0; r < 4; ++r) {
                    float vv = fmaxf(acc[nt][r] * dinv[r], 0.f);
                    xo[((size_t)(b * 2048 + ib + r)) * F + nt * 16 + l15] = f2b(vv);
                }
        }
    }
}

// ---------------- final linear stage 1: [8,131072] fp32 @ [131072,128] fp32
// grid 512, block 256; block p owns k in [p*256,(p+1)*256); writes pbuf[p][b][o].
__global__ void __launch_bounds__(256) k_lin(const float* __restrict__ o3,
                                             const float* __restrict__ Wlin,
                                             float* __restrict__ pbuf) {
    __shared__ float xc[8][256];
    __shared__ float red[8][8][128];          // [kb][b][o] = 32 KB
    const int tid = threadIdx.x;
    const int k0 = blockIdx.x * 256;
    for (int idx = tid; idx < 2048; idx += 256) {
        int bb = idx >> 8, kk = idx & 255;
        xc[bb][kk] = o3[(size_t)bb * 131072 + k0 + kk];
    }
    __syncthreads();
    const int o4 = tid & 31;                  // float4 output group: o = 4*o4..4*o4+3
    const int kb = tid >> 5;                  // k band: 32 k each
    f32x4 acc[8];
#pragma unroll
    for (int bb = 0; bb < 8; ++bb) acc[bb] = (f32x4){0.f, 0.f, 0.f, 0.f};
    const float* wp = Wlin + (size_t)(k0 + kb * 32) * 128 + o4 * 4;
#pragma unroll 4
    for (int k = 0; k < 32; ++k) {
        f32x4 wv = *reinterpret_cast<const f32x4*>(wp + (size_t)k * 128);
#pragma unroll
        for (int bb = 0; bb < 8; ++bb) acc[bb] += wv * xc[bb][kb * 32 + k];
    }
#pragma unroll
    for (int bb = 0; bb < 8; ++bb)
        *reinterpret_cast<f32x4*>(&red[kb][bb][o4 * 4]) = acc[bb];
    __syncthreads();
    // fold 8 k-bands: thread handles 4 flat outputs
    const int f = tid * 4;
    const int bb = f >> 7, o = f & 127;
    f32x4 s = (f32x4){0.f, 0.f, 0.f, 0.f};
#pragma unroll
    for (int k2 = 0; k2 < 8; ++k2) s += *reinterpret_cast<const f32x4*>(&red[k2][bb][o]);
    *reinterpret_cast<f32x4*>(&pbuf[(size_t)blockIdx.x * 1024 + f]) = s;
}

// ---------------- stage 2: fold 512 partials + bias -> out
// grid 64 x 256: block owns 16 outputs; 16 threads/output sum strided partials.
__global__ void __launch_bounds__(256) k_bias(const float* __restrict__ pbuf,
                                              const float* __restrict__ blin,
                                              float* __restrict__ out) {
    __shared__ float red[256];
    const int tid = threadIdx.x;
    const int p16 = tid >> 4;                 // 16 p-groups
    const int fo = tid & 15;
    const int f0 = blockIdx.x * 16;
    float s = 0.f;
#pragma unroll 4
    for (int p = p16; p < 512; p += 16)
        s += pbuf[(size_t)p * 1024 + f0 + fo];
    red[tid] = s;
    __syncthreads();
    if (tid < 16) {
        float t = 0.f;
#pragma unroll
        for (int k = 0; k < 16; ++k) t += red[k * 16 + tid];
        out[f0 + tid] = t + blin[(f0 + tid) & 127];
    }
}

extern "C" void kernel_launch(void* const* d_in, const int* in_sizes, int n_in,
                              void* d_out, int out_size, void* d_ws, size_t ws_size,
                              hipStream_t stream) {
    (void)in_sizes; (void)n_in; (void)out_size;
    const float* x    = (const float*)d_in[0];
    const float* adj  = (const float*)d_in[1];
    const float* W1   = (const float*)d_in[2];
    const float* a1s  = (const float*)d_in[3];
    const float* a1d  = (const float*)d_in[4];
    const float* W2   = (const float*)d_in[5];
    const float* a2s  = (const float*)d_in[6];
    const float* a2d  = (const float*)d_in[7];
    const float* W3   = (const float*)d_in[8];
    const float* a3s  = (const float*)d_in[9];
    const float* a3d  = (const float*)d_in[10];
    const float* Wlin = (const float*)d_in[11];
    const float* blin = (const float*)d_in[12];

    // ---- workspace layout (adaptive; never early-return) ----
    char* ws = (char*)d_ws;
    u16*   h_t = (u16*)ws;                          // 4 MB  [8][F][2048] bf16
    size_t off = (size_t)4 << 20;
    float* esf = (float*)(ws + off); off += 131072; // [8][2048] x (Es,Fs)
    float* edf = (float*)(ws + off); off += 131072; // [8][2048] x (Ed,Fd)
    u16*   Wt1 = (u16*)(ws + off);   off += 32768;
    u16*   Wt2 = (u16*)(ws + off);   off += 32768;
    u16*   Wt3 = (u16*)(ws + off);   off += 16384;
    float* u1s = (float*)(ws + off); off += 512;
    float* u1d = (float*)(ws + off); off += 512;
    float* u2s = (float*)(ws + off); off += 512;
    float* u2d = (float*)(ws + off); off += 512;
    float* u3s = (float*)(ws + off); off += 512;
    float* u3d = (float*)(ws + off); off += 512;
    uint32_t* adjm = (uint32_t*)(ws + off); off += 524288;    // [2048][64] bitmask
    float* pbuf = (float*)(ws + off); off += (size_t)512 * 1024 * 4;  // 2 MB partials
    // activation ping (bf16 [8][2048][128] = 4MB) aliases layer-3 fp32 out
    // ([8][2048][64] fp32 = 4MB): disjoint live ranges. Fallback: alias the x
    // input (16MB fp32; dead after layer-1 k_h; restored by harness pre-launch).
    u16* actA;
    if (ws_size >= off + ((size_t)4 << 20)) {
        actA = (u16*)(ws + off);
    } else {
        actA = (u16*)d_in[0];
    }
    float* o3 = (float*)actA;

    dim3 g(8, 32);
    k_mask<<<512, 256, 0, stream>>>(adj, adjm);
    k_prep<<<161, 256, 0, stream>>>(W1, W2, W3, a1s, a1d, a2s, a2d, a3s, a3d,
                                    Wt1, Wt2, Wt3, u1s, u1d, u2s, u2d, u3s, u3d);

    k_h<128, true ><<<g, 256, 0, stream>>>((const void*)x, Wt1, u1s, u1d, h_t, esf, edf);
    k_attn<128, false><<<g, 512, 0, stream>>>(esf, edf, adjm, h_t, (void*)actA);

    k_h<128, false><<<g, 256, 0, stream>>>((const void*)actA, Wt2, u2s, u2d, h_t, esf, edf);
    k_attn<128, false><<<g, 512, 0, stream>>>(esf, edf, adjm, h_t, (void*)actA);

    k_h<64, false><<<g, 256, 0, stream>>>((const void*)actA, Wt3, u3s, u3d, h_t, esf, edf);
    k_attn<64, true ><<<g, 512, 0, stream>>>(esf, edf, adjm, h_t, (void*)o3);

    k_lin<<<512, 256, 0, stream>>>(o3, Wlin, pbuf);
    k_bias<<<64, 256, 0, stream>>>(pbuf, blin, (float*)d_out);
}